// Round 4
// baseline (615.057 us; speedup 1.0000x reference)
//
#include <hip/hip_runtime.h>
#include <cstdint>
#include <cstddef>

// Problem constants (reference: M=8192, IN=4096, OUT=4096)
#define M_DIM 8192
#define K_DIM 4096
#define N_DIM 4096

// GEMM tile geometry
#define BM 256
#define BN 128
#define BK 64
#define NBUF 3
#define NT (K_DIM / BK)  // 64 K-tiles

typedef unsigned short u16;
typedef __bf16 bf16x8 __attribute__((ext_vector_type(8)));
typedef u16 u16x8 __attribute__((ext_vector_type(8)));
typedef float f32x4 __attribute__((ext_vector_type(4)));

// fp32 -> bf16 round-to-nearest-even (inputs are finite normals; no NaN path)
__device__ __forceinline__ u16 f2bf_rne(float f) {
  uint32_t u = __builtin_bit_cast(uint32_t, f);
  return (u16)((u + 0x7FFFu + ((u >> 16) & 1u)) >> 16);
}
// small int -> bf16 (exact for |i| <= 8)
__device__ __forceinline__ u16 i2bf(int i) {
  return (u16)(__builtin_bit_cast(uint32_t, (float)i) >> 16);
}

#define XBLKS 16384  // M*K/8/256 blocks for the x-conversion half
#define WBLKS 8192   // N*(K/2)/4/256 blocks for the weight-dequant half

// ---- Fused prep: x fp32->bf16 and packed-int4 -> bf16 integer weights ----
__global__ __launch_bounds__(256) void prep(const float* __restrict__ x,
                                            const int* __restrict__ wp,
                                            u16* __restrict__ xb,
                                            u16* __restrict__ wb) {
  const int b = blockIdx.x;
  if (b < XBLKS) {
    size_t t = (size_t)b * 256 + threadIdx.x;
    const float4* xp = (const float4*)x;
    float4 a = xp[2 * t];
    float4 c = xp[2 * t + 1];
    u16x8 r;
    r[0] = f2bf_rne(a.x); r[1] = f2bf_rne(a.y); r[2] = f2bf_rne(a.z); r[3] = f2bf_rne(a.w);
    r[4] = f2bf_rne(c.x); r[5] = f2bf_rne(c.y); r[6] = f2bf_rne(c.z); r[7] = f2bf_rne(c.w);
    ((u16x8*)xb)[t] = r;
  } else {
    size_t t = (size_t)(b - XBLKS) * 256 + threadIdx.x;
    int4 p = ((const int4*)wp)[t];
    u16x8 r;
    int v;
    v = p.x ^ 0x88; r[0] = i2bf((v << 28) >> 28); r[1] = i2bf((v << 24) >> 28);
    v = p.y ^ 0x88; r[2] = i2bf((v << 28) >> 28); r[3] = i2bf((v << 24) >> 28);
    v = p.z ^ 0x88; r[4] = i2bf((v << 28) >> 28); r[5] = i2bf((v << 24) >> 28);
    v = p.w ^ 0x88; r[6] = i2bf((v << 28) >> 28); r[7] = i2bf((v << 24) >> 28);
    ((u16x8*)wb)[t] = r;
  }
}

// --------- bf16 gemm_bt: 256x128 tile, 3-buffer counted-vmcnt pipeline ------
// C[m][n] = (sum_k A[m][k]*B[n][k]) * scale[n] + bias[n]
//
// Pipeline (T3/T4): K-tile t lives in LDS buffer t%3; iteration t stages tile
// t+2 (lookahead 2). Per iteration:
//   1. s_waitcnt vmcnt(6)   -- own tile-t loads (6/tile) are oldest in flight;
//                              tile t+1's 6 loads MAY remain outstanding.
//   2. s_barrier            -- RAW barrier (no vmcnt(0) drain!). After it, all
//                              waves' tile-t loads have landed, and all waves'
//                              tile-(t-1) ds_reads are retired (each wave's
//                              reads drain via lgkmcnt before its MFMAs, which
//                              precede this barrier in program order).
//   3. stage(t+2) -> buf (t+2)%3 == tile (t-1)'s buffer: safe per step 2.
//   4. ds_read tile t frags + 2x16 MFMA (setprio(1) around clusters, T5).
// vmcnt never drains to 0 in the MAIN loop. The FINAL tile is peeled with a
// full vmcnt(0): in steady state vmcnt(6) proves tile t landed because 12 are
// outstanding, but at t=NT-1 only 6 are outstanding, so vmcnt(6) would pass
// without the loads having landed (tail race — fixed by the peel).
//
// Swizzle (verified SQ_LDS_BANK_CONFLICT==0): LDS row = 64 u16 = 128 B = 32
// banks. Thread tid stages global 16B-chunk ((tid&7) ^ (row&7)) into linear
// LDS slot tid&7 (global_load_lds requires linear dest, rule 21); readers
// address slot c ^ (lrow&7). 8 distinct slots across 8 rows -> 32 banks,
// 2 lanes/bank (free per m136).
__global__ __launch_bounds__(512, 2) void gemm_bt_w4a16(
    const u16* __restrict__ A,      // [M_DIM, K_DIM] bf16 bits
    const u16* __restrict__ B,      // [N_DIM, K_DIM] bf16 bits (integer weights)
    const float* __restrict__ scales,
    const float* __restrict__ bias,
    float* __restrict__ C) {
  __shared__ u16 sA[NBUF][BM * BK];  // 3 x 32 KiB = 96 KiB
  __shared__ u16 sB[NBUF][BN * BK];  // 3 x 16 KiB = 48 KiB

  const int tid = threadIdx.x;
  const int lane = tid & 63;
  const int wave = tid >> 6;          // 0..7

  // XCD-aware swizzle (T1): 1024 blocks, nwg%8==0 -> bijective. XCD x gets
  // tiles with bx in [4x, 4x+4): 4 B-panels = 4 MiB ~= its private L2.
  const int flat = blockIdx.x;
  const int swz = (flat & 7) * 128 + (flat >> 3);
  const int bx = swz >> 5;            // 0..31  (N blocks)
  const int by = swz & 31;            // 0..31  (M blocks)
  const int m0 = by * BM;
  const int n0 = bx * BN;

  const int wm = (wave >> 1) * 64;    // 0,64,128,192 (4 M-waves)
  const int wn = (wave & 1) * 64;     // 0,64         (2 N-waves)
  const int lrow = lane & 15;         // row within a 16x16 frag
  const int quad = lane >> 4;         // k-chunk selector; m-subrow for C/D

  f32x4 acc[4][4] = {};

  // Staging map: thread tid covers row tid>>3 (+64 per round), linear chunk
  // slot tid&7; global source chunk XOR-swizzled by row&7 (invariant across
  // rounds since rows step by 64 == 0 mod 8).
  const int srow = tid >> 3;                    // 0..63
  const int schunk = ((tid & 7) ^ (srow & 7)) * 8;
  const u16* ga = A + (size_t)(m0 + srow) * K_DIM + schunk;
  const u16* gb = B + (size_t)(n0 + srow) * K_DIM + schunk;
  const int ldsoff = wave * 1024;               // wave's 8-row slab (8*128B)

  // Stage one K-tile (A: 256x64 = 4 loads, B: 128x64 = 2 loads per thread).
  auto stage = [&](int buf, int kb) {
#pragma unroll
    for (int r = 0; r < 4; ++r)
      __builtin_amdgcn_global_load_lds(
          (const __attribute__((address_space(1))) void*)(ga + (size_t)(r * 64) * K_DIM + kb),
          (__attribute__((address_space(3))) void*)((char*)sA[buf] + r * 8192 + ldsoff),
          16, 0, 0);
#pragma unroll
    for (int r = 0; r < 2; ++r)
      __builtin_amdgcn_global_load_lds(
          (const __attribute__((address_space(1))) void*)(gb + (size_t)(r * 64) * K_DIM + kb),
          (__attribute__((address_space(3))) void*)((char*)sB[buf] + r * 8192 + ldsoff),
          16, 0, 0);
  };

  // Compute one K-tile from buffer `buf`: 2 k-slices x (8 reads + 16 MFMA).
  auto compute = [&](int buf) {
    const u16* bA = sA[buf];
    const u16* bB = sB[buf];
#pragma unroll
    for (int s = 0; s < 2; ++s) {
      const int kc = ((s * 4 + quad) ^ (lrow & 7)) * 8;
      u16x8 af[4], bfr[4];
#pragma unroll
      for (int i = 0; i < 4; ++i)
        af[i] = *(const u16x8*)(bA + (wm + i * 16 + lrow) * BK + kc);
#pragma unroll
      for (int j = 0; j < 4; ++j)
        bfr[j] = *(const u16x8*)(bB + (wn + j * 16 + lrow) * BK + kc);
      __builtin_amdgcn_s_setprio(1);
#pragma unroll
      for (int i = 0; i < 4; ++i)
#pragma unroll
        for (int j = 0; j < 4; ++j)
          acc[i][j] = __builtin_amdgcn_mfma_f32_16x16x32_bf16(
              __builtin_bit_cast(bf16x8, af[i]),
              __builtin_bit_cast(bf16x8, bfr[j]), acc[i][j], 0, 0, 0);
      __builtin_amdgcn_s_setprio(0);
    }
  };

  stage(0, 0);
  stage(1, BK);

  int cur = 0;
#pragma unroll 1
  for (int t = 0; t < NT - 1; ++t) {
    // 12 outstanding (tiles t, t+1); drop to <=6 -> tile t's loads landed.
    asm volatile("s_waitcnt vmcnt(6)" ::: "memory");
    __builtin_amdgcn_s_barrier();          // raw: tile t+1's loads stay in flight
    __builtin_amdgcn_sched_barrier(0);     // pin: nothing crosses the barrier

    if (t + 2 < NT) {
      int pre = cur + 2;
      if (pre >= NBUF) pre -= NBUF;
      stage(pre, (t + 2) * BK);            // overwrites tile t-1's buffer
    }
    compute(cur);
    cur = (cur == NBUF - 1) ? 0 : cur + 1;
  }

  // Peeled final tile: only its own 6 loads are outstanding -> need full drain
  // (vmcnt(6) would pass without them having landed).
  asm volatile("s_waitcnt vmcnt(0)" ::: "memory");
  __builtin_amdgcn_s_barrier();
  __builtin_amdgcn_sched_barrier(0);
  compute(cur);

  // Epilogue: C/D layout col = lane&15 (n), row = quad*4 + reg (m). Apply
  // per-output-row scale + bias here (keeps MFMA inputs exact integers).
#pragma unroll
  for (int j = 0; j < 4; ++j) {
    const int n = n0 + wn + j * 16 + lrow;
    const float sc = scales[n];
    const float bi = bias[n];
#pragma unroll
    for (int i = 0; i < 4; ++i) {
      const int m = m0 + wm + i * 16 + quad * 4;
      float* cp = &C[(size_t)m * N_DIM + n];
#pragma unroll
      for (int r = 0; r < 4; ++r)
        cp[(size_t)r * N_DIM] = acc[i][j][r] * sc + bi;
    }
  }
}

// ---------------- Fallback (ws too small): fp32 direct, correct but slow ----
__global__ __launch_bounds__(256) void fallback_w4a16(
    const float* __restrict__ x, const int* __restrict__ wp,
    const float* __restrict__ scales, const float* __restrict__ bias,
    float* __restrict__ out) {
  const int n = blockIdx.x * 256 + threadIdx.x;
  const int m = blockIdx.y;
  const float* xr = x + (size_t)m * K_DIM;
  const int* wr = wp + (size_t)n * (K_DIM / 2);
  float acc = 0.f;
  for (int j = 0; j < K_DIM / 2; ++j) {
    int w = wr[j] ^ 0x88;
    float lo = (float)((w << 28) >> 28);
    float hi = (float)((w << 24) >> 28);
    acc += xr[2 * j] * lo + xr[2 * j + 1] * hi;
  }
  out[(size_t)m * N_DIM + n] = acc * scales[n] + bias[n];
}

extern "C" void kernel_launch(void* const* d_in, const int* in_sizes, int n_in,
                              void* d_out, int out_size, void* d_ws, size_t ws_size,
                              hipStream_t stream) {
  const float* x = (const float*)d_in[0];
  const int* wp = (const int*)d_in[1];
  const float* sc = (const float*)d_in[2];
  const float* bi = (const float*)d_in[3];
  float* out = (float*)d_out;

  const size_t xb_elems = (size_t)M_DIM * K_DIM;           // 64 MiB as u16
  const size_t wb_elems = (size_t)N_DIM * K_DIM;           // 32 MiB as u16
  const size_t need = (xb_elems + wb_elems) * sizeof(u16); // 100,663,296 B

  if (ws_size >= need) {
    u16* xb = (u16*)d_ws;
    u16* wb = xb + xb_elems;
    prep<<<XBLKS + WBLKS, 256, 0, stream>>>(x, wp, xb, wb);
    gemm_bt_w4a16<<<dim3((N_DIM / BN) * (M_DIM / BM)), 512, 0, stream>>>(xb, wb, sc, bi, out);
  } else {
    fallback_w4a16<<<dim3(N_DIM / 256, M_DIM), 256, 0, stream>>>(x, wp, sc, bi, out);
  }
}

// Round 5
// 469.748 us; speedup vs baseline: 1.3093x; 1.3093x over previous
//
#include <hip/hip_runtime.h>
#include <cstdint>
#include <cstddef>

// Problem constants (reference: M=8192, IN=4096, OUT=4096)
#define M_DIM 8192
#define K_DIM 4096
#define N_DIM 4096

// GEMM tile geometry
#define BM 256
#define BN 256
#define BK 64
#define NT (K_DIM / BK)  // 64 K-tiles

typedef unsigned short u16;
typedef __bf16 bf16x8 __attribute__((ext_vector_type(8)));
typedef u16 u16x8 __attribute__((ext_vector_type(8)));
typedef float f32x4 __attribute__((ext_vector_type(4)));

// fp32 -> bf16 round-to-nearest-even (inputs are finite normals; no NaN path)
__device__ __forceinline__ u16 f2bf_rne(float f) {
  uint32_t u = __builtin_bit_cast(uint32_t, f);
  return (u16)((u + 0x7FFFu + ((u >> 16) & 1u)) >> 16);
}
// small int -> bf16 (exact for |i| <= 8)
__device__ __forceinline__ u16 i2bf(int i) {
  return (u16)(__builtin_bit_cast(uint32_t, (float)i) >> 16);
}

#define XBLKS 16384  // M*K/8/256 blocks for the x-conversion half
#define WBLKS 8192   // N*(K/2)/4/256 blocks for the weight-dequant half

// ---- Fused prep: x fp32->bf16 and packed-int4 -> bf16 integer weights ----
__global__ __launch_bounds__(256) void prep(const float* __restrict__ x,
                                            const int* __restrict__ wp,
                                            u16* __restrict__ xb,
                                            u16* __restrict__ wb) {
  const int b = blockIdx.x;
  if (b < XBLKS) {
    size_t t = (size_t)b * 256 + threadIdx.x;
    const float4* xp = (const float4*)x;
    float4 a = xp[2 * t];
    float4 c = xp[2 * t + 1];
    u16x8 r;
    r[0] = f2bf_rne(a.x); r[1] = f2bf_rne(a.y); r[2] = f2bf_rne(a.z); r[3] = f2bf_rne(a.w);
    r[4] = f2bf_rne(c.x); r[5] = f2bf_rne(c.y); r[6] = f2bf_rne(c.z); r[7] = f2bf_rne(c.w);
    ((u16x8*)xb)[t] = r;
  } else {
    size_t t = (size_t)(b - XBLKS) * 256 + threadIdx.x;
    int4 p = ((const int4*)wp)[t];
    u16x8 r;
    int v;
    v = p.x ^ 0x88; r[0] = i2bf((v << 28) >> 28); r[1] = i2bf((v << 24) >> 28);
    v = p.y ^ 0x88; r[2] = i2bf((v << 28) >> 28); r[3] = i2bf((v << 24) >> 28);
    v = p.z ^ 0x88; r[4] = i2bf((v << 28) >> 28); r[5] = i2bf((v << 24) >> 28);
    v = p.w ^ 0x88; r[6] = i2bf((v << 28) >> 28); r[7] = i2bf((v << 24) >> 28);
    ((u16x8*)wb)[t] = r;
  }
}

// ---- bf16 gemm_bt: 256x256 tile, half-tile counted-vmcnt pipeline ---------
// C[m][n] = (sum_k A[m][k]*B[n][k]) * scale[n] + bias[n]
//
// K-tile = 4 half-tiles (A0/A1 = A rows 0-127/128-255, B0/B1 likewise), each
// 128x64x2B = 16 KiB = 2 global_load_lds per thread. Buffers: A0 has 3 slots
// (rotating T%3), A1/B0/B1 have 2 (T&1) -> 144 KiB LDS.
//
// Per iteration T (ledger-verified):
//  1. stage A0(T+1) -> slot (T+1)%3. That slot last held A0(T-2), whose reads
//     finished in iter T-2, certified by >=1 intervening barrier. Safe BEFORE
//     this iter's barrier -> makes the wait counted.
//  2. s_waitcnt vmcnt(2): per-wave outstanding = [A0(T)(2), A1/B0/B1(T)(6),
//     A0(T+1)(2)]; waits for the 8 oldest = ALL of tile T. Never drains.
//  3. raw s_barrier: certifies (a) every wave's tile-T loads landed (each
//     passed its own vmcnt(2)), (b) every wave's tile-(T-1) reads retired ->
//     staging A1/B0/B1(T+1) into buf[(T+1)&1] (which held T-1) is now safe.
//  4. 4 sub-phases: {4x ds_read_b128 A-frags; one half-tile stage; setprio(1);
//     16 MFMA; setprio(0); sched_barrier(0)}. B-frags (4 reads) loaded at each
//     s-slice start, reused across the two i-halves. No intra-tile barriers:
//     all cross-wave hazards are tile-granular (audited: any buffer written in
//     iter region X is disjoint from buffers readable by waves <=1 barrier
//     behind).
//  Tail: last tile has no younger loads -> peeled vmcnt(0) (one drain total).
//
// Swizzle (verified SQ_LDS_BANK_CONFLICT==0): LDS row = 64 u16 = 128 B = 32
// banks. Thread tid stages global 16B-chunk ((tid&7) ^ (srow&7)) into linear
// LDS slot tid&7 (global_load_lds needs linear dest, rule 21); readers address
// slot chunk ^ (lrow&7). Staged rows step by 64 == 0 mod 8 -> key invariant.
__global__ __launch_bounds__(512, 2) void gemm_bt_w4a16(
    const u16* __restrict__ A,      // [M_DIM, K_DIM] bf16 bits
    const u16* __restrict__ B,      // [N_DIM, K_DIM] bf16 bits (integer weights)
    const float* __restrict__ scales,
    const float* __restrict__ bias,
    float* __restrict__ C) {
  __shared__ u16 sA0[3][128 * 64];  // 48 KiB, slot = T%3
  __shared__ u16 sA1[2][128 * 64];  // 32 KiB, slot = T&1
  __shared__ u16 sB0[2][128 * 64];  // 32 KiB
  __shared__ u16 sB1[2][128 * 64];  // 32 KiB   total 144 KiB

  const int tid = threadIdx.x;
  const int lane = tid & 63;
  const int wave = tid >> 6;          // 0..7
  const int m0 = blockIdx.y * BM;
  const int n0 = blockIdx.x * BN;

  const int wm = (wave >> 2) * 128;   // 0 or 128   (2 M-waves)
  const int wn = (wave & 3) * 64;     // 0,64,128,192 (4 N-waves)
  const int lrow = lane & 15;         // row within a 16x16 frag
  const int quad = lane >> 4;         // k-chunk selector; m-subrow for C/D
  const int brw0 = wn & 64;           // B row base within its half

  f32x4 acc[8][4] = {};

  // Staging map: thread tid covers half-row srow=tid>>3 and srow+64 (2 loads),
  // linear chunk slot tid&7; global source chunk XOR-swizzled by srow&7.
  const int srow = tid >> 3;                    // 0..63
  const int schunk = ((tid & 7) ^ (srow & 7)) * 8;
  const u16* ga = A + (size_t)(m0 + srow) * K_DIM + schunk;  // A half0 row srow
  const u16* gb = B + (size_t)(n0 + srow) * K_DIM + schunk;
  const int dst0 = tid * 16;                    // LDS byte offset, load r adds 8192

#define GLDS(gp, lp)                                                      \
  __builtin_amdgcn_global_load_lds(                                       \
      (const __attribute__((address_space(1))) void*)(gp),                \
      (__attribute__((address_space(3))) void*)(lp), 16, 0, 0)

  // Stage one half-tile (2 loads: rows srow and srow+64 of the half).
  auto stA0 = [&](int slot, int T) {
    const u16* g = ga + (size_t)T * BK;
    char* d = (char*)sA0[slot] + dst0;
    GLDS(g, d);
    GLDS(g + (size_t)64 * K_DIM, d + 8192);
  };
  auto stA1 = [&](int b, int T) {
    const u16* g = ga + (size_t)128 * K_DIM + (size_t)T * BK;
    char* d = (char*)sA1[b] + dst0;
    GLDS(g, d);
    GLDS(g + (size_t)64 * K_DIM, d + 8192);
  };
  auto stB0 = [&](int b, int T) {
    const u16* g = gb + (size_t)T * BK;
    char* d = (char*)sB0[b] + dst0;
    GLDS(g, d);
    GLDS(g + (size_t)64 * K_DIM, d + 8192);
  };
  auto stB1 = [&](int b, int T) {
    const u16* g = gb + (size_t)128 * K_DIM + (size_t)T * BK;
    char* d = (char*)sB1[b] + dst0;
    GLDS(g, d);
    GLDS(g + (size_t)64 * K_DIM, d + 8192);
  };

  // Prologue: tile 0 fully staged (8 loads).
  stA0(0, 0); stA1(0, 0); stB0(0, 0); stB1(0, 0);

  int a0slot = 0;  // slot of tile T's A0
#pragma unroll 1
  for (int T = 0; T < NT; ++T) {
    const int buf = T & 1;
    const int nbuf = buf ^ 1;
    const bool more = (T + 1 < NT);
    int a0next = a0slot + 1; if (a0next == 3) a0next = 0;

    if (more) {
      stA0(a0next, T + 1);                       // counted-wait enabler
      asm volatile("s_waitcnt vmcnt(2)" ::: "memory");
    } else {
      asm volatile("s_waitcnt vmcnt(0)" ::: "memory");  // peeled tail drain
    }
    __builtin_amdgcn_s_barrier();                // raw: young loads stay in flight
    __builtin_amdgcn_sched_barrier(0);

    const u16* aH = (wave < 4) ? sA0[a0slot] : sA1[buf];
    const u16* bH = (wn < 128) ? sB0[buf] : sB1[buf];

#pragma unroll
    for (int s = 0; s < 2; ++s) {
      const int kc = ((s * 4 + quad) ^ (lrow & 7)) * 8;
      u16x8 bfr[4];
#pragma unroll
      for (int j = 0; j < 4; ++j)
        bfr[j] = *(const u16x8*)(bH + (brw0 + j * 16 + lrow) * BK + kc);
#pragma unroll
      for (int ih = 0; ih < 2; ++ih) {
        u16x8 af[4];
#pragma unroll
        for (int i = 0; i < 4; ++i)
          af[i] = *(const u16x8*)(aH + (ih * 64 + i * 16 + lrow) * BK + kc);
        if (more) {                              // one half-tile stage per sub-phase
          if (s == 0 && ih == 0) stA1(nbuf, T + 1);
          if (s == 0 && ih == 1) stB0(nbuf, T + 1);
          if (s == 1 && ih == 0) stB1(nbuf, T + 1);
        }
        __builtin_amdgcn_s_setprio(1);
#pragma unroll
        for (int i = 0; i < 4; ++i)
#pragma unroll
          for (int j = 0; j < 4; ++j)
            acc[ih * 4 + i][j] = __builtin_amdgcn_mfma_f32_16x16x32_bf16(
                __builtin_bit_cast(bf16x8, af[i]),
                __builtin_bit_cast(bf16x8, bfr[j]), acc[ih * 4 + i][j], 0, 0, 0);
        __builtin_amdgcn_s_setprio(0);
        __builtin_amdgcn_sched_barrier(0);       // pin sub-phase interleave
      }
    }
    a0slot = a0next;
  }

  // Epilogue: C/D layout col = lane&15 (n), row = quad*4 + reg (m). Apply
  // per-output-row scale + bias here (keeps MFMA inputs exact integers).
#pragma unroll
  for (int j = 0; j < 4; ++j) {
    const int n = n0 + wn + j * 16 + lrow;
    const float sc = scales[n];
    const float bi = bias[n];
#pragma unroll
    for (int i = 0; i < 8; ++i) {
      const int m = m0 + wm + i * 16 + quad * 4;
      float* cp = &C[(size_t)m * N_DIM + n];
#pragma unroll
      for (int r = 0; r < 4; ++r)
        cp[(size_t)r * N_DIM] = acc[i][j][r] * sc + bi;
    }
  }
#undef GLDS
}

// ---------------- Fallback (ws too small): fp32 direct, correct but slow ----
__global__ __launch_bounds__(256) void fallback_w4a16(
    const float* __restrict__ x, const int* __restrict__ wp,
    const float* __restrict__ scales, const float* __restrict__ bias,
    float* __restrict__ out) {
  const int n = blockIdx.x * 256 + threadIdx.x;
  const int m = blockIdx.y;
  const float* xr = x + (size_t)m * K_DIM;
  const int* wr = wp + (size_t)n * (K_DIM / 2);
  float acc = 0.f;
  for (int j = 0; j < K_DIM / 2; ++j) {
    int w = wr[j] ^ 0x88;
    float lo = (float)((w << 28) >> 28);
    float hi = (float)((w << 24) >> 28);
    acc += xr[2 * j] * lo + xr[2 * j + 1] * hi;
  }
  out[(size_t)m * N_DIM + n] = acc * scales[n] + bias[n];
}

extern "C" void kernel_launch(void* const* d_in, const int* in_sizes, int n_in,
                              void* d_out, int out_size, void* d_ws, size_t ws_size,
                              hipStream_t stream) {
  const float* x = (const float*)d_in[0];
  const int* wp = (const int*)d_in[1];
  const float* sc = (const float*)d_in[2];
  const float* bi = (const float*)d_in[3];
  float* out = (float*)d_out;

  const size_t xb_elems = (size_t)M_DIM * K_DIM;           // 64 MiB as u16
  const size_t wb_elems = (size_t)N_DIM * K_DIM;           // 32 MiB as u16
  const size_t need = (xb_elems + wb_elems) * sizeof(u16); // 100,663,296 B

  if (ws_size >= need) {
    u16* xb = (u16*)d_ws;
    u16* wb = xb + xb_elems;
    prep<<<XBLKS + WBLKS, 256, 0, stream>>>(x, wp, xb, wb);
    gemm_bt_w4a16<<<dim3(N_DIM / BN, M_DIM / BM), 512, 0, stream>>>(xb, wb, sc, bi, out);
  } else {
    fallback_w4a16<<<dim3(N_DIM / 256, M_DIM), 256, 0, stream>>>(x, wp, sc, bi, out);
  }
}

// Round 6
// 460.013 us; speedup vs baseline: 1.3370x; 1.0212x over previous
//
#include <hip/hip_runtime.h>
#include <cstdint>
#include <cstddef>

// Problem constants (reference: M=8192, IN=4096, OUT=4096)
#define M_DIM 8192
#define K_DIM 4096
#define N_DIM 4096

// GEMM tile geometry
#define BM 256
#define BN 256
#define BK 64
#define NT (K_DIM / BK)  // 64 K-tiles

typedef unsigned short u16;
typedef __bf16 bf16x8 __attribute__((ext_vector_type(8)));
typedef u16 u16x8 __attribute__((ext_vector_type(8)));
typedef float f32x4 __attribute__((ext_vector_type(4)));

// fp32 -> bf16 round-to-nearest-even (inputs are finite normals; no NaN path)
__device__ __forceinline__ u16 f2bf_rne(float f) {
  uint32_t u = __builtin_bit_cast(uint32_t, f);
  return (u16)((u + 0x7FFFu + ((u >> 16) & 1u)) >> 16);
}
// small int -> bf16 (exact for |i| <= 8)
__device__ __forceinline__ u16 i2bf(int i) {
  return (u16)(__builtin_bit_cast(uint32_t, (float)i) >> 16);
}

#define XBLKS 16384  // M*K/8/256 blocks for the x-conversion half
#define WBLKS 8192   // N*(K/2)/4/256 blocks for the weight-dequant half

// ---- Fused prep: x fp32->bf16 and packed-int4 -> bf16 integer weights ----
__global__ __launch_bounds__(256) void prep(const float* __restrict__ x,
                                            const int* __restrict__ wp,
                                            u16* __restrict__ xb,
                                            u16* __restrict__ wb) {
  const int b = blockIdx.x;
  if (b < XBLKS) {
    size_t t = (size_t)b * 256 + threadIdx.x;
    const float4* xp = (const float4*)x;
    float4 a = xp[2 * t];
    float4 c = xp[2 * t + 1];
    u16x8 r;
    r[0] = f2bf_rne(a.x); r[1] = f2bf_rne(a.y); r[2] = f2bf_rne(a.z); r[3] = f2bf_rne(a.w);
    r[4] = f2bf_rne(c.x); r[5] = f2bf_rne(c.y); r[6] = f2bf_rne(c.z); r[7] = f2bf_rne(c.w);
    ((u16x8*)xb)[t] = r;
  } else {
    size_t t = (size_t)(b - XBLKS) * 256 + threadIdx.x;
    int4 p = ((const int4*)wp)[t];
    u16x8 r;
    int v;
    v = p.x ^ 0x88; r[0] = i2bf((v << 28) >> 28); r[1] = i2bf((v << 24) >> 28);
    v = p.y ^ 0x88; r[2] = i2bf((v << 28) >> 28); r[3] = i2bf((v << 24) >> 28);
    v = p.z ^ 0x88; r[4] = i2bf((v << 28) >> 28); r[5] = i2bf((v << 24) >> 28);
    v = p.w ^ 0x88; r[6] = i2bf((v << 28) >> 28); r[7] = i2bf((v << 24) >> 28);
    ((u16x8*)wb)[t] = r;
  }
}

// ---- bf16 gemm_bt: 256x256 tile, half-tile counted-vmcnt pipeline ---------
// C[m][n] = (sum_k A[m][k]*B[n][k]) * scale[n] + bias[n]
//
// Sync skeleton (unchanged from the measured-correct round-5 kernel):
// K-tile = 4 half-tiles (A0/A1 rows 0-127/128-255, B0/B1), each 128x64x2B =
// 16 KiB = 2 global_load_lds/thread. A0 has 3 slots (T%3), A1/B0/B1 have 2
// (T&1) -> 144 KiB. Per iter T: stage A0(T+1) (its slot held A0(T-2), reads
// long retired) -> s_waitcnt vmcnt(2) (waits the 8 oldest = all of tile T;
// never drains) -> raw s_barrier (certifies tile T landed everywhere AND tile
// T-1 reads retired -> staging A1/B0/B1(T+1) over tile T-1's buffers is safe)
// -> compute tile T with the 3 remaining stages spread inside. Tail peeled
// with one vmcnt(0).
//
// Scheduling (NEW this round): exactly TWO sched_barrier(0) per tile —
// anti-hoist after s_barrier, anti-sink at tile end (a tile-T MFMA + its
// lgkm wait sunk past the next barrier would let an outstanding ds_read race
// other waves' stages into tile T's buffer). NO fences inside the tile: the
// 4 MFMA clusters + 24 ds_reads + 3 stages are one free scheduling region.
// Fragment loads are hand-rotated (named sets, static indices per rule #20):
// sub-phase p+1's ds_reads issue before sub-phase p's MFMA cluster, so LDS
// latency is exposed once per tile, not 4x. (Round-5's per-cluster
// sched_barrier(0) caused exactly the measured 49% MfmaUtil — m141 pattern.)
//
// Swizzle (verified SQ_LDS_BANK_CONFLICT==0): LDS row = 64 u16 = 128 B = 32
// banks. Thread tid stages global 16B-chunk ((tid&7) ^ (srow&7)) into linear
// LDS slot tid&7 (global_load_lds needs linear dest, rule 21); readers address
// slot chunk ^ (lrow&7). Staged rows step by 64 == 0 mod 8 -> key invariant.
__global__ __launch_bounds__(512, 2) void gemm_bt_w4a16(
    const u16* __restrict__ A,      // [M_DIM, K_DIM] bf16 bits
    const u16* __restrict__ B,      // [N_DIM, K_DIM] bf16 bits (integer weights)
    const float* __restrict__ scales,
    const float* __restrict__ bias,
    float* __restrict__ C) {
  __shared__ u16 sA0[3][128 * 64];  // 48 KiB, slot = T%3
  __shared__ u16 sA1[2][128 * 64];  // 32 KiB, slot = T&1
  __shared__ u16 sB0[2][128 * 64];  // 32 KiB
  __shared__ u16 sB1[2][128 * 64];  // 32 KiB   total 144 KiB

  const int tid = threadIdx.x;
  const int lane = tid & 63;
  const int wave = tid >> 6;          // 0..7
  const int m0 = blockIdx.y * BM;
  const int n0 = blockIdx.x * BN;

  const int wm = (wave >> 2) * 128;   // 0 or 128   (2 M-waves)
  const int wn = (wave & 3) * 64;     // 0,64,128,192 (4 N-waves)
  const int lrow = lane & 15;         // row within a 16x16 frag
  const int quad = lane >> 4;         // k-chunk selector; m-subrow for C/D
  const int brw0 = wn & 64;           // B row base within its half

  f32x4 acc[8][4] = {};

  // Staging map: thread tid covers half-rows srow and srow+64 (2 loads),
  // linear chunk slot tid&7; global source chunk XOR-swizzled by srow&7.
  const int srow = tid >> 3;                    // 0..63
  const int schunk = ((tid & 7) ^ (srow & 7)) * 8;
  const u16* ga = A + (size_t)(m0 + srow) * K_DIM + schunk;  // A half0 row srow
  const u16* gb = B + (size_t)(n0 + srow) * K_DIM + schunk;
  const int dst0 = tid * 16;                    // LDS byte offset; +8192 for row+64

#define GLDS(gp, lp)                                                      \
  __builtin_amdgcn_global_load_lds(                                       \
      (const __attribute__((address_space(1))) void*)(gp),                \
      (__attribute__((address_space(3))) void*)(lp), 16, 0, 0)

  // Stage one half-tile (2 loads: rows srow and srow+64 of the half).
  auto stA0 = [&](int slot, int T) {
    const u16* g = ga + (size_t)T * BK;
    char* d = (char*)sA0[slot] + dst0;
    GLDS(g, d);
    GLDS(g + (size_t)64 * K_DIM, d + 8192);
  };
  auto stA1 = [&](int b, int T) {
    const u16* g = ga + (size_t)128 * K_DIM + (size_t)T * BK;
    char* d = (char*)sA1[b] + dst0;
    GLDS(g, d);
    GLDS(g + (size_t)64 * K_DIM, d + 8192);
  };
  auto stB0 = [&](int b, int T) {
    const u16* g = gb + (size_t)T * BK;
    char* d = (char*)sB0[b] + dst0;
    GLDS(g, d);
    GLDS(g + (size_t)64 * K_DIM, d + 8192);
  };
  auto stB1 = [&](int b, int T) {
    const u16* g = gb + (size_t)128 * K_DIM + (size_t)T * BK;
    char* d = (char*)sB1[b] + dst0;
    GLDS(g, d);
    GLDS(g + (size_t)64 * K_DIM, d + 8192);
  };

  struct frag4 { u16x8 v[4]; };

  // Prologue: tile 0 fully staged (8 loads).
  stA0(0, 0); stA1(0, 0); stB0(0, 0); stB1(0, 0);

  int a0slot = 0;  // slot of tile T's A0
#pragma unroll 1
  for (int T = 0; T < NT; ++T) {
    const int buf = T & 1;
    const int nbuf = buf ^ 1;
    const bool more = (T + 1 < NT);
    int a0next = a0slot + 1; if (a0next == 3) a0next = 0;

    if (more) {
      stA0(a0next, T + 1);                       // counted-wait enabler
      asm volatile("s_waitcnt vmcnt(2)" ::: "memory");
    } else {
      asm volatile("s_waitcnt vmcnt(0)" ::: "memory");  // peeled tail drain
    }
    __builtin_amdgcn_s_barrier();                // raw: young loads stay in flight
    __builtin_amdgcn_sched_barrier(0);           // anti-hoist fence

    const u16* aH = (wave < 4) ? sA0[a0slot] : sA1[buf];
    const u16* bH = (wn < 128) ? sB0[buf] : sB1[buf];

    const int kc0 = ((0 * 4 + quad) ^ (lrow & 7)) * 8;
    const int kc1 = ((1 * 4 + quad) ^ (lrow & 7)) * 8;

    auto ldA = [&](int ih, int kc) {
      frag4 f;
#pragma unroll
      for (int i = 0; i < 4; ++i)
        f.v[i] = *(const u16x8*)(aH + (ih * 64 + i * 16 + lrow) * BK + kc);
      return f;
    };
    auto ldB = [&](int kc) {
      frag4 f;
#pragma unroll
      for (int j = 0; j < 4; ++j)
        f.v[j] = *(const u16x8*)(bH + (brw0 + j * 16 + lrow) * BK + kc);
      return f;
    };

    // Software-pipelined 4 sub-phases: reads for p+1 issue before MFMA of p.
    frag4 bfr0 = ldB(kc0);
    frag4 afA = ldA(0, kc0);

    frag4 afB = ldA(1, kc0);                     // prefetch sub-phase 1
    if (more) stA1(nbuf, T + 1);
    __builtin_amdgcn_s_setprio(1);
#pragma unroll
    for (int i = 0; i < 4; ++i)
#pragma unroll
      for (int j = 0; j < 4; ++j)
        acc[i][j] = __builtin_amdgcn_mfma_f32_16x16x32_bf16(
            __builtin_bit_cast(bf16x8, afA.v[i]),
            __builtin_bit_cast(bf16x8, bfr0.v[j]), acc[i][j], 0, 0, 0);
    __builtin_amdgcn_s_setprio(0);

    frag4 afA2 = ldA(0, kc1);                    // prefetch sub-phase 2
    frag4 bfr1 = ldB(kc1);
    if (more) stB0(nbuf, T + 1);
    __builtin_amdgcn_s_setprio(1);
#pragma unroll
    for (int i = 0; i < 4; ++i)
#pragma unroll
      for (int j = 0; j < 4; ++j)
        acc[4 + i][j] = __builtin_amdgcn_mfma_f32_16x16x32_bf16(
            __builtin_bit_cast(bf16x8, afB.v[i]),
            __builtin_bit_cast(bf16x8, bfr0.v[j]), acc[4 + i][j], 0, 0, 0);
    __builtin_amdgcn_s_setprio(0);

    frag4 afB2 = ldA(1, kc1);                    // prefetch sub-phase 3
    if (more) stB1(nbuf, T + 1);
    __builtin_amdgcn_s_setprio(1);
#pragma unroll
    for (int i = 0; i < 4; ++i)
#pragma unroll
      for (int j = 0; j < 4; ++j)
        acc[i][j] = __builtin_amdgcn_mfma_f32_16x16x32_bf16(
            __builtin_bit_cast(bf16x8, afA2.v[i]),
            __builtin_bit_cast(bf16x8, bfr1.v[j]), acc[i][j], 0, 0, 0);
    __builtin_amdgcn_s_setprio(0);

    __builtin_amdgcn_s_setprio(1);
#pragma unroll
    for (int i = 0; i < 4; ++i)
#pragma unroll
      for (int j = 0; j < 4; ++j)
        acc[4 + i][j] = __builtin_amdgcn_mfma_f32_16x16x32_bf16(
            __builtin_bit_cast(bf16x8, afB2.v[i]),
            __builtin_bit_cast(bf16x8, bfr1.v[j]), acc[4 + i][j], 0, 0, 0);
    __builtin_amdgcn_s_setprio(0);

    __builtin_amdgcn_sched_barrier(0);           // anti-sink fence (tile ends)
    a0slot = a0next;
  }

  // Epilogue: C/D layout col = lane&15 (n), row = quad*4 + reg (m). Apply
  // per-output-row scale + bias here (keeps MFMA inputs exact integers).
#pragma unroll
  for (int j = 0; j < 4; ++j) {
    const int n = n0 + wn + j * 16 + lrow;
    const float sc = scales[n];
    const float bi = bias[n];
#pragma unroll
    for (int i = 0; i < 8; ++i) {
      const int m = m0 + wm + i * 16 + quad * 4;
      float* cp = &C[(size_t)m * N_DIM + n];
#pragma unroll
      for (int r = 0; r < 4; ++r)
        cp[(size_t)r * N_DIM] = acc[i][j][r] * sc + bi;
    }
  }
#undef GLDS
}

// ---------------- Fallback (ws too small): fp32 direct, correct but slow ----
__global__ __launch_bounds__(256) void fallback_w4a16(
    const float* __restrict__ x, const int* __restrict__ wp,
    const float* __restrict__ scales, const float* __restrict__ bias,
    float* __restrict__ out) {
  const int n = blockIdx.x * 256 + threadIdx.x;
  const int m = blockIdx.y;
  const float* xr = x + (size_t)m * K_DIM;
  const int* wr = wp + (size_t)n * (K_DIM / 2);
  float acc = 0.f;
  for (int j = 0; j < K_DIM / 2; ++j) {
    int w = wr[j] ^ 0x88;
    float lo = (float)((w << 28) >> 28);
    float hi = (float)((w << 24) >> 28);
    acc += xr[2 * j] * lo + xr[2 * j + 1] * hi;
  }
  out[(size_t)m * N_DIM + n] = acc * scales[n] + bias[n];
}

extern "C" void kernel_launch(void* const* d_in, const int* in_sizes, int n_in,
                              void* d_out, int out_size, void* d_ws, size_t ws_size,
                              hipStream_t stream) {
  const float* x = (const float*)d_in[0];
  const int* wp = (const int*)d_in[1];
  const float* sc = (const float*)d_in[2];
  const float* bi = (const float*)d_in[3];
  float* out = (float*)d_out;

  const size_t xb_elems = (size_t)M_DIM * K_DIM;           // 64 MiB as u16
  const size_t wb_elems = (size_t)N_DIM * K_DIM;           // 32 MiB as u16
  const size_t need = (xb_elems + wb_elems) * sizeof(u16); // 100,663,296 B

  if (ws_size >= need) {
    u16* xb = (u16*)d_ws;
    u16* wb = xb + xb_elems;
    prep<<<XBLKS + WBLKS, 256, 0, stream>>>(x, wp, xb, wb);
    gemm_bt_w4a16<<<dim3(N_DIM / BN, M_DIM / BM), 512, 0, stream>>>(xb, wb, sc, bi, out);
  } else {
    fallback_w4a16<<<dim3(N_DIM / 256, M_DIM), 256, 0, stream>>>(x, wp, sc, bi, out);
  }
}